// Round 9
// baseline (275.605 us; speedup 1.0000x reference)
//
#include <hip/hip_runtime.h>
#include <hip/hip_bf16.h>
#include <math.h>

#define BATCH 8
#define NATOMS 192
#define NTOT (BATCH*NATOMS)

using short8 = __attribute__((ext_vector_type(8))) short;
using f32x4  = __attribute__((ext_vector_type(4))) float;

__device__ __forceinline__ float fast_rcp(float x){ return __builtin_amdgcn_rcpf(x); }
__device__ __forceinline__ float sigmoid_f(float x){ return fast_rcp(1.0f+__expf(-x)); }
__device__ __forceinline__ float silu_f(float x){ return x*fast_rcp(1.0f+__expf(-x)); }
__device__ __forceinline__ float softplus_f(float x){ return fmaxf(x,0.0f)+log1pf(expf(-fabsf(x))); }
__device__ __forceinline__ unsigned short f2bf(float x){
  __hip_bfloat16 h = __float2bfloat16(x);
  return __builtin_bit_cast(unsigned short, h);
}

__device__ __forceinline__ float wave_sum(float v){
  v += __shfl_xor(v, 1);
  v += __shfl_xor(v, 2);
  v += __shfl_xor(v, 4);
  v += __shfl_xor(v, 8);
  v += __shfl_xor(v, 16);
  v += __shfl_xor(v, 32);
  return v;
}
__device__ __forceinline__ float sum32(float v){
  v += __shfl_xor(v, 1);
  v += __shfl_xor(v, 2);
  v += __shfl_xor(v, 4);
  v += __shfl_xor(v, 8);
  v += __shfl_xor(v, 16);
  return v;
}
__device__ __forceinline__ float sum16(float v){
  v += __shfl_xor(v, 1);
  v += __shfl_xor(v, 2);
  v += __shfl_xor(v, 4);
  v += __shfl_xor(v, 8);
  return v;
}

struct KP {
  const float *xyz, *pdf, *t;
  const float *emb_in_w, *emb_in_b, *emb_out_w, *emb_out_b, *x_out_w, *x_out_b;
  const float *pdf_w, *pdf_b;
  const float *g1w, *g1b, *g2w, *g2b, *g3w, *g3b, *gamma0, *gamma1;
  const float *lnhg, *lnhb, *lnxg, *lnxb;
  const float *e1w, *e1b, *e2w, *e2b, *eiw, *eib;
  const float *n1w, *n1b, *n2w, *n2b;
  const float *c1w, *c1b, *c2w, *c2b, *c3w, *c3b;
  float *temb, *pdfe;
  unsigned short *e2wb, *c2wb;
  float *hln0, *hln1, *ue0, *uc0, *vep0, *vcp0, *ue1, *uc1, *vep1, *vcp1;
  float *xb0, *xb1;
  float *out;
};

// ---------------- prelude: 0..79 pdf dot; 80..87 gamma(b); 88..119 wprep ----
__global__ __launch_bounds__(128) void k_prelude(KP P)
{
  __shared__ float s_sm[8];
  const int bx = blockIdx.x, tid = threadIdx.x;
  const int wv = tid >> 6, ln = tid & 63;

  if (bx < 80){
    const int b = bx / 10, o = bx % 10;
    const float* pb = P.pdf + b*3000;
    const float* wb = P.pdf_w + o*3000;
    float p = 0.f;
    for (int k = tid; k < 3000; k += 128) p = fmaf(pb[k], wb[k], p);
    p = wave_sum(p);
    if (ln == 0) s_sm[wv] = p;
    __syncthreads();
    if (tid == 0) P.pdfe[b*10 + o] = s_sm[0] + s_sm[1] + P.pdf_b[o];
  } else if (bx < 88){
    const int b = bx - 80;
    const float w1 = softplus_f(P.g1w[0]);
    const float b1 = P.g1b[0];
    const float tn = P.t[b] * (1.0f/1000.0f);
    const float l1_0 = b1;
    const float l1_1 = w1 + b1;
    const float l1_t = fmaf(w1, tn, b1);
    float a0 = 0.f, a1 = 0.f, at = 0.f;
    for (int k = tid; k < 1024; k += 128){
      float w2 = softplus_f(P.g2w[k]);
      float bb = P.g2b[k];
      float w3 = softplus_f(P.g3w[k]);
      a0 += sigmoid_f(fmaf(w2, l1_0, bb)) * w3;
      a1 += sigmoid_f(fmaf(w2, l1_1, bb)) * w3;
      at += sigmoid_f(fmaf(w2, l1_t, bb)) * w3;
    }
    float vals[3] = {a0, a1, at};
#pragma unroll
    for (int r = 0; r < 3; ++r){
      float v = wave_sum(vals[r]);
      if (ln == 0) s_sm[r*2 + wv] = v;
    }
    __syncthreads();
    if (tid == 0){
      const float b3 = P.g3b[0];
      const float g0  = l1_0 + s_sm[0] + s_sm[1] + b3;
      const float g1v = l1_1 + s_sm[2] + s_sm[3] + b3;
      const float gt  = l1_t + s_sm[4] + s_sm[5] + b3;
      P.temb[b] = P.gamma0[0] + (P.gamma1[0] - P.gamma0[0]) * (gt - g0) / (g1v - g0);
    }
  } else {
    const int g = (bx - 88)*128 + tid;        // 32*128 = 4096
    P.e2wb[g] = f2bf(P.e2w[g]);
    P.c2wb[g] = f2bf(P.c2w[g]);
  }
}

// ---------------- embed + layer-0 precompute (1 node / 128-thr block) -------
__global__ __launch_bounds__(128) void k_embed(KP P)
{
  __shared__ float s_hl[32];
  const int nid = blockIdx.x;
  const int tid = threadIdx.x;
  const int wv = tid >> 6, ln = tid & 63;
  const int b = nid / NATOMS;
  if (tid < 32){
    const int f = tid;
    const float* w = P.emb_in_w + f*12;
    float a = P.emb_in_b[f];
    a = fmaf(P.xyz[nid*4 + 3], w[0], a);
    a = fmaf(P.temb[b], w[1], a);
    const float* pe = P.pdfe + b*10;
#pragma unroll
    for (int q = 0; q < 10; ++q) a = fmaf(pe[q], w[2+q], a);
    const float m = sum32(a) * (1.0f/32.0f);
    const float d = a - m;
    const float v = sum32(d*d);
    const float r = rsqrtf(v*(1.0f/32.0f) + 1e-5f);
    const float hlv = fmaf(d*r, P.lnhg[f], P.lnhb[f]);
    s_hl[f] = hlv;
    P.hln0[(size_t)nid*32 + f] = hlv;
    if (f < 3) P.xb0[(size_t)nid*3 + f] = P.xyz[nid*4 + f];
  }
  __syncthreads();
  if (ln < 32){
    const int f = ln;
    const float* W = ((wv == 0) ? P.e1w : P.c1w) + f*66;
    float sv = ((wv == 0) ? P.e1b : P.c1b)[f], su = 0.f;
#pragma unroll
    for (int k = 0; k < 32; ++k){ sv = fmaf(s_hl[k], W[k], sv); su = fmaf(s_hl[k], W[32+k], su); }
    if (wv == 0){ P.vep0[(size_t)nid*32 + f] = sv; P.ue0[(size_t)nid*32 + f] = su; }
    else        { P.vcp0[(size_t)nid*32 + f] = sv; P.uc0[(size_t)nid*32 + f] = su; }
  }
}

// ---------------- layer kernel: 4 waves / node, 6 tiles / wave --------------
// Block = node, 256 thr (r6 structure — best measured). wv0/wv1 = edge
// (tiles t%2==wv), wv2/wv3 = cor. Swapped-operand MFMA: D[f][j],
// f=quad*4+reg, j=n16. Bias folded into MFMA C. u-loads software-pipelined
// (prefetch t+2) via 32-bit offsets off a uniform base. Geometry in SoA LDS
// (per-quad same-address broadcasts, conflict-free; r7's [192][8] AoS hit
// 485K conflicts). launch_bounds(256,6): 6 blocks/CU = full co-residency of
// the 1536-block grid (r6's (256,5) forced a 256-block tail round); VGPR cap
// ~85 >> 48 measured demand (r7 lesson: never cap below demand).
__global__ __launch_bounds__(256, 6) void k_layer(KP P, int l, int last,
    const float* __restrict__ xcur, float* __restrict__ xnxt,
    const float* __restrict__ hlnC, float* __restrict__ hlnN,
    const float* __restrict__ ueC, const float* __restrict__ ucC,
    const float* __restrict__ vepC, const float* __restrict__ vcpC,
    float* __restrict__ ueN, float* __restrict__ ucN,
    float* __restrict__ vepN, float* __restrict__ vcpN)
{
  __shared__ float s_d2[192], s_d0[192];
  __shared__ float s_dfx[192], s_dfy[192], s_dfz[192], s_dist[192];
  __shared__ float s_mgp[2][32];    // m_agg partials per edge wave
  __shared__ float s_pxp[2][4];     // px,py,pz partials per cor wave
  __shared__ float s_hv[32];
  __shared__ float s_n1[32];
  __shared__ float s_hl[32];

  const int nid = blockIdx.x;
  const int b = nid / NATOMS;
  const int i = nid - b*NATOMS;
  const int base = b*NATOMS;
  const int tid = threadIdx.x;
  const int wv = tid >> 6, lane = tid & 63;
  const int n16 = lane & 15, quad = lane >> 4;
  const int is_edge = (wv < 2);
  const int half = wv & 1;

  // ---- geometry staging (SoA) ----
  if (tid < NATOMS){
    const int j = tid;
    const float* xi_p = xcur + (size_t)nid*3;
    const float xi0 = xi_p[0], xi1 = xi_p[1], xi2 = xi_p[2];
    const float* x0i = P.xyz + (size_t)nid*4;
    const float q0i = x0i[0], q1i = x0i[1], q2i = x0i[2];
    const float* xj_p = xcur + (size_t)(base + j)*3;
    const float dfx = xi0 - xj_p[0], dfy = xi1 - xj_p[1], dfz = xi2 - xj_p[2];
    const float d2 = dfx*dfx + dfy*dfy + dfz*dfz;
    const float dist = sqrtf(fmaxf(d2, 1e-12f));
    const float* x0j = P.xyz + (size_t)(base + j)*4;
    const float q0 = q0i - x0j[0], q1 = q1i - x0j[1], q2 = q2i - x0j[2];
    const float d0 = sqrtf(fmaxf(q0*q0 + q1*q1 + q2*q2, 1e-12f));
    s_d2[j] = d2;  s_d0[j] = d0;
    s_dfx[j] = dfx; s_dfy[j] = dfy; s_dfz[j] = dfz; s_dist[j] = dist;
  }

  // ---- per-wave invariants ----
  const float* e1wl = (is_edge ? P.e1w : P.c1w) + l*2112;
  const float* vp   = (is_edge ? vepC : vcpC) + (size_t)nid*32;
  const float* uu   = is_edge ? ueC : ucC;
  const unsigned short* w2b = (is_edge ? P.e2wb : P.c2wb) + l*1024;
  const float* bias2 = (is_edge ? P.e2b : P.c2b) + l*32;
  const float* wout  = (is_edge ? P.eiw : P.c3w) + l*32;
  const float  bout  = (is_edge ? P.eib : P.c3b)[l];

  float vp8[8], wA[8], wB[8];
#pragma unroll
  for (int q = 0; q < 8; ++q){
    const int k = quad*8 + q;
    vp8[q] = vp[k];
    wA[q] = e1wl[k*66 + 64];
    wB[q] = e1wl[k*66 + 65];
  }
  const short8 wb0 = *(const short8*)(w2b + n16*32 + quad*8);
  const short8 wb1 = *(const short8*)(w2b + 512 + n16*32 + quad*8);

  f32x4 cb0, cb1;
  float wAo[4], wBo[4];
#pragma unroll
  for (int r = 0; r < 4; ++r){
    cb0[r] = bias2[quad*4 + r];
    cb1[r] = bias2[16 + quad*4 + r];
    wAo[r] = wout[quad*4 + r];
    wBo[r] = wout[16 + quad*4 + r];
  }

  __syncthreads();   // geometry ready

  float acc0[4] = {0.f,0.f,0.f,0.f};   // edge: m_agg[f=quad*4+r]
  float acc1[4] = {0.f,0.f,0.f,0.f};   // edge: m_agg[f=16+quad*4+r]
  float px = 0.f, py = 0.f, pz = 0.f;  // cor accumulators

  // ---- 6 j-tiles per wave (t%2 == half), pipelined, barrier-free ----
  const float* up = uu + base*32;
  int uoff = (half*16 + n16)*32 + quad*8;
  f32x4 cua = *(const f32x4*)(up + uoff);
  f32x4 cub = *(const f32x4*)(up + uoff + 4);
#pragma unroll
  for (int it = 0; it < 6; ++it){
    const int t = half + it*2;
    const int j = t*16 + n16;
    f32x4 nua = cua, nub = cub;
    if (it < 5){
      nua = *(const f32x4*)(up + uoff + 1024);
      nub = *(const f32x4*)(up + uoff + 1024 + 4);
    }
    uoff += 1024;                      // 2 tiles * 16 j * 32 f
    const float d2 = s_d2[j], d0 = s_d0[j];
    short8 a;
#pragma unroll
    for (int q = 0; q < 4; ++q)
      a[q] = (short)f2bf(silu_f(fmaf(d2, wA[q], fmaf(d0, wB[q], vp8[q] + cua[q]))));
#pragma unroll
    for (int q = 0; q < 4; ++q)
      a[4+q] = (short)f2bf(silu_f(fmaf(d2, wA[4+q], fmaf(d0, wB[4+q], vp8[4+q] + cub[q]))));

    const f32x4 A0 = __builtin_amdgcn_mfma_f32_16x16x32_bf16(wb0, a, cb0, 0, 0, 0);
    const f32x4 A1 = __builtin_amdgcn_mfma_f32_16x16x32_bf16(wb1, a, cb1, 0, 0, 0);

    float m20[4], m21[4];
#pragma unroll
    for (int r = 0; r < 4; ++r){
      m20[r] = silu_f(A0[r]);
      m21[r] = silu_f(A1[r]);
    }
    float gp = 0.f;
#pragma unroll
    for (int r = 0; r < 4; ++r) gp += m20[r]*wAo[r] + m21[r]*wBo[r];
    gp += __shfl_xor(gp, 16);
    gp += __shfl_xor(gp, 32);

    if (is_edge){
      const float e = (j == i) ? 0.0f : sigmoid_f(gp + bout);
#pragma unroll
      for (int r = 0; r < 4; ++r){
        acc0[r] = fmaf(e, m20[r], acc0[r]);
        acc1[r] = fmaf(e, m21[r], acc1[r]);
      }
    } else {
      const float s = (gp + bout) * fast_rcp(s_dist[j] + 1.0f);
      px = fmaf(s, s_dfx[j], px);
      py = fmaf(s, s_dfy[j], py);
      pz = fmaf(s, s_dfz[j], pz);
    }
    cua = nua; cub = nub;
  }

  // ---- end reductions + partial stores ----
  if (is_edge){
#pragma unroll
    for (int r = 0; r < 4; ++r){
      acc0[r] = sum16(acc0[r]);
      acc1[r] = sum16(acc1[r]);
    }
    if (n16 == 0){
#pragma unroll
      for (int r = 0; r < 4; ++r){
        s_mgp[half][quad*4 + r] = acc0[r];
        s_mgp[half][16 + quad*4 + r] = acc1[r];
      }
    }
  } else {
    px = sum16(px); py = sum16(py); pz = sum16(pz);
    if (lane == 0){
      s_pxp[half][0] = px; s_pxp[half][1] = py; s_pxp[half][2] = pz;
    }
    if (half == 1 && lane < 32) s_hv[lane] = hlnC[(size_t)nid*32 + lane];
  }
  __syncthreads();

  // ---- post phase ----
  if (wv == 0){
    if (lane < 32){
      const int f = lane;
      float a = P.n1b[l*32 + f];
      const float* w1 = P.n1w + l*2048 + f*64;
#pragma unroll
      for (int k = 0; k < 32; ++k) a = fmaf(s_hv[k], w1[k], a);
#pragma unroll
      for (int k = 0; k < 32; ++k) a = fmaf(s_mgp[0][k] + s_mgp[1][k], w1[32+k], a);
      s_n1[f] = silu_f(a);
    }
  } else if (wv == 1){
    const float tx = s_pxp[0][0] + s_pxp[1][0];
    const float ty = s_pxp[0][1] + s_pxp[1][1];
    const float tz = s_pxp[0][2] + s_pxp[1][2];
    const float* xr = xcur + (size_t)nid*3;
    const float x0 = xr[0], x1 = xr[1], x2 = xr[2];
    const float mx = (x0 + x1 + x2) * (1.0f/3.0f);
    const float v0 = x0-mx, v1 = x1-mx, v2 = x2-mx;
    const float r = rsqrtf((v0*v0 + v1*v1 + v2*v2)*(1.0f/3.0f) + 1e-5f);
    const float xn0 = fmaf((x0 - mx)*r, P.lnxg[l*3+0], P.lnxb[l*3+0]) + tx;
    const float xn1 = fmaf((x1 - mx)*r, P.lnxg[l*3+1], P.lnxb[l*3+1]) + ty;
    const float xn2 = fmaf((x2 - mx)*r, P.lnxg[l*3+2], P.lnxb[l*3+2]) + tz;
    if (!last){
      if (lane == 0){
        float* xo = xnxt + (size_t)nid*3;
        xo[0] = xn0; xo[1] = xn1; xo[2] = xn2;
      }
    } else if (lane < 3){
      const float xn[3] = {xn0, xn1, xn2};
      float o = P.x_out_b[lane];
      o = fmaf(xn[0], P.x_out_w[lane*3 + 0], o);
      o = fmaf(xn[1], P.x_out_w[lane*3 + 1], o);
      o = fmaf(xn[2], P.x_out_w[lane*3 + 2], o);
      P.out[(size_t)nid*4 + lane] = o - P.xyz[(size_t)nid*4 + lane];
    }
  }
  __syncthreads();

  if (wv == 0 && lane < 32){
    const int f = lane;
    float o = P.n2b[l*32 + f];
    const float* w2 = P.n2w + l*1024 + f*32;
#pragma unroll
    for (int k = 0; k < 32; ++k) o = fmaf(s_n1[k], w2[k], o);
    const float ho = s_hv[f] + o;
    if (last){
      float hp = sum32(ho * P.emb_out_w[f]);
      if (f == 0) P.out[(size_t)nid*4 + 3] = hp + P.emb_out_b[0];
    } else {
      const int nx = l + 1;
      const float m = sum32(ho) * (1.0f/32.0f);
      const float d = ho - m;
      const float v = sum32(d*d);
      const float r = rsqrtf(v*(1.0f/32.0f) + 1e-5f);
      const float hlv = fmaf(d*r, P.lnhg[nx*32 + f], P.lnhb[nx*32 + f]);
      s_hl[f] = hlv;
      hlnN[(size_t)nid*32 + f] = hlv;
    }
  }
  if (!last){
    __syncthreads();
    if (wv < 2 && lane < 32){
      const int f = lane;
      const int nx = l + 1;
      const float* W = ((wv == 0) ? P.e1w : P.c1w) + nx*2112 + f*66;
      float sv = ((wv == 0) ? P.e1b : P.c1b)[nx*32 + f], su = 0.f;
#pragma unroll
      for (int k = 0; k < 32; ++k){ sv = fmaf(s_hl[k], W[k], sv); su = fmaf(s_hl[k], W[32+k], su); }
      if (wv == 0){ vepN[(size_t)nid*32 + f] = sv; ueN[(size_t)nid*32 + f] = su; }
      else        { vcpN[(size_t)nid*32 + f] = sv; ucN[(size_t)nid*32 + f] = su; }
    }
  }
}

extern "C" void kernel_launch(void* const* d_in, const int* in_sizes, int n_in,
                              void* d_out, int out_size, void* d_ws, size_t ws_size,
                              hipStream_t stream)
{
  float* ws   = (float*)d_ws;

  KP P;
  P.xyz      = (const float*)d_in[0];
  P.pdf      = (const float*)d_in[1];
  P.t        = (const float*)d_in[2];
  P.emb_in_w = (const float*)d_in[3];
  P.emb_in_b = (const float*)d_in[4];
  P.emb_out_w= (const float*)d_in[5];
  P.emb_out_b= (const float*)d_in[6];
  P.x_out_w  = (const float*)d_in[7];
  P.x_out_b  = (const float*)d_in[8];
  P.pdf_w    = (const float*)d_in[9];
  P.pdf_b    = (const float*)d_in[10];
  P.g1w      = (const float*)d_in[11];
  P.g1b      = (const float*)d_in[12];
  P.g2w      = (const float*)d_in[13];
  P.g2b      = (const float*)d_in[14];
  P.g3w      = (const float*)d_in[15];
  P.g3b      = (const float*)d_in[16];
  P.gamma0   = (const float*)d_in[17];
  P.gamma1   = (const float*)d_in[18];
  P.lnhg     = (const float*)d_in[19];
  P.lnhb     = (const float*)d_in[20];
  P.lnxg     = (const float*)d_in[21];
  P.lnxb     = (const float*)d_in[22];
  P.e1w      = (const float*)d_in[23];
  P.e1b      = (const float*)d_in[24];
  P.e2w      = (const float*)d_in[25];
  P.e2b      = (const float*)d_in[26];
  P.eiw      = (const float*)d_in[27];
  P.eib      = (const float*)d_in[28];
  P.n1w      = (const float*)d_in[29];
  P.n1b      = (const float*)d_in[30];
  P.n2w      = (const float*)d_in[31];
  P.n2b      = (const float*)d_in[32];
  P.c1w      = (const float*)d_in[33];
  P.c1b      = (const float*)d_in[34];
  P.c2w      = (const float*)d_in[35];
  P.c2b      = (const float*)d_in[36];
  P.c3w      = (const float*)d_in[37];
  P.c3b      = (const float*)d_in[38];

  P.temb = ws;                              // 8
  P.pdfe = ws + 8;                          // 80 (pad to 96)
  P.e2wb = (unsigned short*)(ws + 96);      // 4096 ushort
  P.c2wb = P.e2wb + 4096;                   // 4096 ushort
  float* p = ws + 96 + 4096;                // (8192 ushort = 4096 floats)
  P.hln0 = p; p += NTOT*32;
  P.hln1 = p; p += NTOT*32;
  P.ue0  = p; p += NTOT*32;
  P.uc0  = p; p += NTOT*32;
  P.vep0 = p; p += NTOT*32;
  P.vcp0 = p; p += NTOT*32;
  P.ue1  = p; p += NTOT*32;
  P.uc1  = p; p += NTOT*32;
  P.vep1 = p; p += NTOT*32;
  P.vcp1 = p; p += NTOT*32;
  P.xb0  = p; p += NTOT*3;
  P.xb1  = p; p += NTOT*3;
  P.out  = (float*)d_out;

  k_prelude<<<120, 128, 0, stream>>>(P);
  k_embed<<<NTOT, 128, 0, stream>>>(P);

  float* xcur = P.xb0; float* xnxt = P.xb1;
  float* hlnC = P.hln0; float* hlnN = P.hln1;
  float* ueC = P.ue0;  float* ucC = P.uc0;  float* vepC = P.vep0; float* vcpC = P.vcp0;
  float* ueN = P.ue1;  float* ucN = P.uc1;  float* vepN = P.vep1; float* vcpN = P.vcp1;
  for (int l = 0; l < 4; ++l){
    k_layer<<<NTOT, 256, 0, stream>>>(P, l, (l == 3) ? 1 : 0, xcur, xnxt,
        hlnC, hlnN, ueC, ucC, vepC, vcpC, ueN, ucN, vepN, vcpN);
    float* tp;
    tp = hlnC; hlnC = hlnN; hlnN = tp;
    tp = ueC;  ueC  = ueN;  ueN  = tp;
    tp = ucC;  ucC  = ucN;  ucN  = tp;
    tp = vepC; vepC = vepN; vepN = tp;
    tp = vcpC; vcpC = vcpN; vcpN = tp;
    tp = xcur; xcur = xnxt; xnxt = tp;
  }
}

// Round 10
// 235.209 us; speedup vs baseline: 1.1717x; 1.1717x over previous
//
#include <hip/hip_runtime.h>
#include <hip/hip_bf16.h>
#include <math.h>

#define BATCH 8
#define NATOMS 192
#define NTOT (BATCH*NATOMS)

using short8 = __attribute__((ext_vector_type(8))) short;
using f32x4  = __attribute__((ext_vector_type(4))) float;

__device__ __forceinline__ float fast_rcp(float x){ return __builtin_amdgcn_rcpf(x); }
__device__ __forceinline__ float sigmoid_f(float x){ return fast_rcp(1.0f+__expf(-x)); }
__device__ __forceinline__ float silu_f(float x){ return x*fast_rcp(1.0f+__expf(-x)); }
__device__ __forceinline__ float softplus_f(float x){ return fmaxf(x,0.0f)+log1pf(expf(-fabsf(x))); }
__device__ __forceinline__ unsigned short f2bf(float x){
  __hip_bfloat16 h = __float2bfloat16(x);
  return __builtin_bit_cast(unsigned short, h);
}

__device__ __forceinline__ float wave_sum(float v){
  v += __shfl_xor(v, 1);
  v += __shfl_xor(v, 2);
  v += __shfl_xor(v, 4);
  v += __shfl_xor(v, 8);
  v += __shfl_xor(v, 16);
  v += __shfl_xor(v, 32);
  return v;
}
__device__ __forceinline__ float sum32(float v){
  v += __shfl_xor(v, 1);
  v += __shfl_xor(v, 2);
  v += __shfl_xor(v, 4);
  v += __shfl_xor(v, 8);
  v += __shfl_xor(v, 16);
  return v;
}
__device__ __forceinline__ float sum16(float v){
  v += __shfl_xor(v, 1);
  v += __shfl_xor(v, 2);
  v += __shfl_xor(v, 4);
  v += __shfl_xor(v, 8);
  return v;
}

struct KP {
  const float *xyz, *pdf, *t;
  const float *emb_in_w, *emb_in_b, *emb_out_w, *emb_out_b, *x_out_w, *x_out_b;
  const float *pdf_w, *pdf_b;
  const float *g1w, *g1b, *g2w, *g2b, *g3w, *g3b, *gamma0, *gamma1;
  const float *lnhg, *lnhb, *lnxg, *lnxb;
  const float *e1w, *e1b, *e2w, *e2b, *eiw, *eib;
  const float *n1w, *n1b, *n2w, *n2b;
  const float *c1w, *c1b, *c2w, *c2b, *c3w, *c3b;
  float *temb, *pdfe;
  unsigned short *e2wb, *c2wb;
  float *hln0, *hln1, *ue0, *uc0, *vep0, *vcp0, *ue1, *uc1, *vep1, *vcp1;
  float *xb0, *xb1;
  float *out;
};

// ---------------- prelude: 0..79 pdf dot; 80..87 gamma(b); 88..119 wprep ----
__global__ __launch_bounds__(128) void k_prelude(KP P)
{
  __shared__ float s_sm[8];
  const int bx = blockIdx.x, tid = threadIdx.x;
  const int wv = tid >> 6, ln = tid & 63;

  if (bx < 80){
    const int b = bx / 10, o = bx % 10;
    const float* pb = P.pdf + b*3000;
    const float* wb = P.pdf_w + o*3000;
    float p = 0.f;
    for (int k = tid; k < 3000; k += 128) p = fmaf(pb[k], wb[k], p);
    p = wave_sum(p);
    if (ln == 0) s_sm[wv] = p;
    __syncthreads();
    if (tid == 0) P.pdfe[b*10 + o] = s_sm[0] + s_sm[1] + P.pdf_b[o];
  } else if (bx < 88){
    const int b = bx - 80;
    const float w1 = softplus_f(P.g1w[0]);
    const float b1 = P.g1b[0];
    const float tn = P.t[b] * (1.0f/1000.0f);
    const float l1_0 = b1;
    const float l1_1 = w1 + b1;
    const float l1_t = fmaf(w1, tn, b1);
    float a0 = 0.f, a1 = 0.f, at = 0.f;
    for (int k = tid; k < 1024; k += 128){
      float w2 = softplus_f(P.g2w[k]);
      float bb = P.g2b[k];
      float w3 = softplus_f(P.g3w[k]);
      a0 += sigmoid_f(fmaf(w2, l1_0, bb)) * w3;
      a1 += sigmoid_f(fmaf(w2, l1_1, bb)) * w3;
      at += sigmoid_f(fmaf(w2, l1_t, bb)) * w3;
    }
    float vals[3] = {a0, a1, at};
#pragma unroll
    for (int r = 0; r < 3; ++r){
      float v = wave_sum(vals[r]);
      if (ln == 0) s_sm[r*2 + wv] = v;
    }
    __syncthreads();
    if (tid == 0){
      const float b3 = P.g3b[0];
      const float g0  = l1_0 + s_sm[0] + s_sm[1] + b3;
      const float g1v = l1_1 + s_sm[2] + s_sm[3] + b3;
      const float gt  = l1_t + s_sm[4] + s_sm[5] + b3;
      P.temb[b] = P.gamma0[0] + (P.gamma1[0] - P.gamma0[0]) * (gt - g0) / (g1v - g0);
    }
  } else {
    const int g = (bx - 88)*128 + tid;        // 32*128 = 4096
    P.e2wb[g] = f2bf(P.e2w[g]);
    P.c2wb[g] = f2bf(P.c2w[g]);
  }
}

// ---------------- embed + layer-0 precompute (1 node / 128-thr block) -------
__global__ __launch_bounds__(128) void k_embed(KP P)
{
  __shared__ float s_hl[32];
  const int nid = blockIdx.x;
  const int tid = threadIdx.x;
  const int wv = tid >> 6, ln = tid & 63;
  const int b = nid / NATOMS;
  if (tid < 32){
    const int f = tid;
    const float* w = P.emb_in_w + f*12;
    float a = P.emb_in_b[f];
    a = fmaf(P.xyz[nid*4 + 3], w[0], a);
    a = fmaf(P.temb[b], w[1], a);
    const float* pe = P.pdfe + b*10;
#pragma unroll
    for (int q = 0; q < 10; ++q) a = fmaf(pe[q], w[2+q], a);
    const float m = sum32(a) * (1.0f/32.0f);
    const float d = a - m;
    const float v = sum32(d*d);
    const float r = rsqrtf(v*(1.0f/32.0f) + 1e-5f);
    const float hlv = fmaf(d*r, P.lnhg[f], P.lnhb[f]);
    s_hl[f] = hlv;
    P.hln0[(size_t)nid*32 + f] = hlv;
    if (f < 3) P.xb0[(size_t)nid*3 + f] = P.xyz[nid*4 + f];
  }
  __syncthreads();
  if (ln < 32){
    const int f = ln;
    const float* W = ((wv == 0) ? P.e1w : P.c1w) + f*66;
    float sv = ((wv == 0) ? P.e1b : P.c1b)[f], su = 0.f;
#pragma unroll
    for (int k = 0; k < 32; ++k){ sv = fmaf(s_hl[k], W[k], sv); su = fmaf(s_hl[k], W[32+k], su); }
    if (wv == 0){ P.vep0[(size_t)nid*32 + f] = sv; P.ue0[(size_t)nid*32 + f] = su; }
    else        { P.vcp0[(size_t)nid*32 + f] = sv; P.uc0[(size_t)nid*32 + f] = su; }
  }
}

// ---------------- layer kernel: swapped-operand MFMA, 4 waves / node --------
// EXACT r5 structure (best measured, 235.6 us) with ONE delta: edg2/cor2
// bias folded into the MFMA C operand (strict removal of 8 VALU adds/tile;
// fp32 accumulation order identical). Everything else untouched — r6-r9's
// SoA/prefetch/occupancy experiments all measured neutral-to-negative.
// Block = node, 256 thr. wv0/wv1 = edge (tiles t%2==wv), wv2/wv3 = cor.
// mfma(W_frag, m1_frag): D[f][j] with f=quad*4+reg (REGISTER), j=n16 (lane).
__global__ __launch_bounds__(256, 4) void k_layer(KP P, int l, int last,
    const float* __restrict__ xcur, float* __restrict__ xnxt,
    const float* __restrict__ hlnC, float* __restrict__ hlnN,
    const float* __restrict__ ueC, const float* __restrict__ ucC,
    const float* __restrict__ vepC, const float* __restrict__ vcpC,
    float* __restrict__ ueN, float* __restrict__ ucN,
    float* __restrict__ vepN, float* __restrict__ vcpN)
{
  __shared__ float s_geo[192][6];   // dfx,dfy,dfz,d2,d0,dist
  __shared__ float s_mgp[2][32];    // m_agg partials (per edge wave)
  __shared__ float s_pxp[2][4];     // px,py,pz partials (per cor wave)
  __shared__ float s_hv[32];
  __shared__ float s_n1[32];
  __shared__ float s_hl[32];

  const int nid = blockIdx.x;
  const int b = nid / NATOMS;
  const int i = nid - b*NATOMS;
  const int base = b*NATOMS;
  const int tid = threadIdx.x;
  const int wv = tid >> 6, lane = tid & 63;
  const int n16 = lane & 15, quad = lane >> 4;
  const int is_edge = (wv < 2);
  const int half = wv & 1;

  // ---- geometry staging ----
  {
    const float* xi_p = xcur + (size_t)nid*3;
    const float xi0 = xi_p[0], xi1 = xi_p[1], xi2 = xi_p[2];
    const float* x0i = P.xyz + (size_t)nid*4;
    const float q0i = x0i[0], q1i = x0i[1], q2i = x0i[2];
    for (int j = tid; j < NATOMS; j += 256){
      const float* xj_p = xcur + (size_t)(base + j)*3;
      const float dfx = xi0 - xj_p[0], dfy = xi1 - xj_p[1], dfz = xi2 - xj_p[2];
      const float d2 = dfx*dfx + dfy*dfy + dfz*dfz;
      const float dist = sqrtf(fmaxf(d2, 1e-12f));
      const float* x0j = P.xyz + (size_t)(base + j)*4;
      const float q0 = q0i - x0j[0], q1 = q1i - x0j[1], q2 = q2i - x0j[2];
      const float d0 = sqrtf(fmaxf(q0*q0 + q1*q1 + q2*q2, 1e-12f));
      s_geo[j][0] = dfx; s_geo[j][1] = dfy; s_geo[j][2] = dfz;
      s_geo[j][3] = d2;  s_geo[j][4] = d0;  s_geo[j][5] = dist;
    }
  }

  // ---- per-wave invariants ----
  const float* e1wl = (is_edge ? P.e1w : P.c1w) + l*2112;
  const float* vp   = (is_edge ? vepC : vcpC) + (size_t)nid*32;
  const float* uu   = is_edge ? ueC : ucC;
  const unsigned short* w2b = (is_edge ? P.e2wb : P.c2wb) + l*1024;
  const float* bias2 = (is_edge ? P.e2b : P.c2b) + l*32;
  const float* wout  = (is_edge ? P.eiw : P.c3w) + l*32;
  const float  bout  = (is_edge ? P.eib : P.c3b)[l];

  float vp8[8], wA[8], wB[8];
#pragma unroll
  for (int q = 0; q < 8; ++q){
    const int k = quad*8 + q;
    vp8[q] = vp[k];
    wA[q] = e1wl[k*66 + 64];
    wB[q] = e1wl[k*66 + 65];
  }
  const short8 wb0 = *(const short8*)(w2b + n16*32 + quad*8);
  const short8 wb1 = *(const short8*)(w2b + 512 + n16*32 + quad*8);

  f32x4 cb0, cb1;
  float wAo[4], wBo[4];
#pragma unroll
  for (int r = 0; r < 4; ++r){
    cb0[r] = bias2[quad*4 + r];
    cb1[r] = bias2[16 + quad*4 + r];
    wAo[r] = wout[quad*4 + r];
    wBo[r] = wout[16 + quad*4 + r];
  }

  __syncthreads();   // geometry ready

  float acc0[4] = {0.f,0.f,0.f,0.f};   // edge: m_agg[f=quad*4+r]
  float acc1[4] = {0.f,0.f,0.f,0.f};   // edge: m_agg[f=16+quad*4+r]
  float px = 0.f, py = 0.f, pz = 0.f;  // cor accumulators

  // ---- 6 j-tiles per wave (t%2 == half), barrier-free ----
#pragma unroll 3
  for (int t = half; t < 12; t += 2){
    const int j = t*16 + n16;
    const float d2 = s_geo[j][3], d0 = s_geo[j][4];
    const float* ur = uu + (size_t)(base + j)*32 + quad*8;
    const f32x4 ua = *(const f32x4*)ur;
    const f32x4 ub = *(const f32x4*)(ur + 4);
    short8 a;
#pragma unroll
    for (int q = 0; q < 4; ++q)
      a[q] = (short)f2bf(silu_f(fmaf(d2, wA[q], fmaf(d0, wB[q], vp8[q] + ua[q]))));
#pragma unroll
    for (int q = 0; q < 4; ++q)
      a[4+q] = (short)f2bf(silu_f(fmaf(d2, wA[4+q], fmaf(d0, wB[4+q], vp8[4+q] + ub[q]))));

    const f32x4 A0 = __builtin_amdgcn_mfma_f32_16x16x32_bf16(wb0, a, cb0, 0, 0, 0);
    const f32x4 A1 = __builtin_amdgcn_mfma_f32_16x16x32_bf16(wb1, a, cb1, 0, 0, 0);

    float m20[4], m21[4];
#pragma unroll
    for (int r = 0; r < 4; ++r){
      m20[r] = silu_f(A0[r]);
      m21[r] = silu_f(A1[r]);
    }
    float gp = 0.f;
#pragma unroll
    for (int r = 0; r < 4; ++r) gp += m20[r]*wAo[r] + m21[r]*wBo[r];
    gp += __shfl_xor(gp, 16);
    gp += __shfl_xor(gp, 32);

    if (is_edge){
      const float e = (j == i) ? 0.0f : sigmoid_f(gp + bout);
#pragma unroll
      for (int r = 0; r < 4; ++r){
        acc0[r] = fmaf(e, m20[r], acc0[r]);
        acc1[r] = fmaf(e, m21[r], acc1[r]);
      }
    } else {
      const float s = (gp + bout) * fast_rcp(s_geo[j][5] + 1.0f);
      px = fmaf(s, s_geo[j][0], px);
      py = fmaf(s, s_geo[j][1], py);
      pz = fmaf(s, s_geo[j][2], pz);
    }
  }

  // ---- end reductions + partial stores ----
  if (is_edge){
#pragma unroll
    for (int r = 0; r < 4; ++r){
      acc0[r] = sum16(acc0[r]);
      acc1[r] = sum16(acc1[r]);
    }
    if (n16 == 0){
#pragma unroll
      for (int r = 0; r < 4; ++r){
        s_mgp[half][quad*4 + r] = acc0[r];
        s_mgp[half][16 + quad*4 + r] = acc1[r];
      }
    }
  } else {
    px = sum16(px); py = sum16(py); pz = sum16(pz);
    if (lane == 0){
      s_pxp[half][0] = px; s_pxp[half][1] = py; s_pxp[half][2] = pz;
    }
    if (half == 1 && lane < 32) s_hv[lane] = hlnC[(size_t)nid*32 + lane];
  }
  __syncthreads();

  // ---- post phase ----
  if (wv == 0){
    if (lane < 32){
      const int f = lane;
      float a = P.n1b[l*32 + f];
      const float* w1 = P.n1w + l*2048 + f*64;
#pragma unroll
      for (int k = 0; k < 32; ++k) a = fmaf(s_hv[k], w1[k], a);
#pragma unroll
      for (int k = 0; k < 32; ++k) a = fmaf(s_mgp[0][k] + s_mgp[1][k], w1[32+k], a);
      s_n1[f] = silu_f(a);
    }
  } else if (wv == 1){
    const float tx = s_pxp[0][0] + s_pxp[1][0];
    const float ty = s_pxp[0][1] + s_pxp[1][1];
    const float tz = s_pxp[0][2] + s_pxp[1][2];
    const float* xr = xcur + (size_t)nid*3;
    const float x0 = xr[0], x1 = xr[1], x2 = xr[2];
    const float mx = (x0 + x1 + x2) * (1.0f/3.0f);
    const float v0 = x0-mx, v1 = x1-mx, v2 = x2-mx;
    const float r = rsqrtf((v0*v0 + v1*v1 + v2*v2)*(1.0f/3.0f) + 1e-5f);
    const float xn0 = fmaf((x0 - mx)*r, P.lnxg[l*3+0], P.lnxb[l*3+0]) + tx;
    const float xn1 = fmaf((x1 - mx)*r, P.lnxg[l*3+1], P.lnxb[l*3+1]) + ty;
    const float xn2 = fmaf((x2 - mx)*r, P.lnxg[l*3+2], P.lnxb[l*3+2]) + tz;
    if (!last){
      if (lane == 0){
        float* xo = xnxt + (size_t)nid*3;
        xo[0] = xn0; xo[1] = xn1; xo[2] = xn2;
      }
    } else if (lane < 3){
      const float xn[3] = {xn0, xn1, xn2};
      float o = P.x_out_b[lane];
      o = fmaf(xn[0], P.x_out_w[lane*3 + 0], o);
      o = fmaf(xn[1], P.x_out_w[lane*3 + 1], o);
      o = fmaf(xn[2], P.x_out_w[lane*3 + 2], o);
      P.out[(size_t)nid*4 + lane] = o - P.xyz[(size_t)nid*4 + lane];
    }
  }
  __syncthreads();

  if (wv == 0 && lane < 32){
    const int f = lane;
    float o = P.n2b[l*32 + f];
    const float* w2 = P.n2w + l*1024 + f*32;
#pragma unroll
    for (int k = 0; k < 32; ++k) o = fmaf(s_n1[k], w2[k], o);
    const float ho = s_hv[f] + o;
    if (last){
      float hp = sum32(ho * P.emb_out_w[f]);
      if (f == 0) P.out[(size_t)nid*4 + 3] = hp + P.emb_out_b[0];
    } else {
      const int nx = l + 1;
      const float m = sum32(ho) * (1.0f/32.0f);
      const float d = ho - m;
      const float v = sum32(d*d);
      const float r = rsqrtf(v*(1.0f/32.0f) + 1e-5f);
      const float hlv = fmaf(d*r, P.lnhg[nx*32 + f], P.lnhb[nx*32 + f]);
      s_hl[f] = hlv;
      hlnN[(size_t)nid*32 + f] = hlv;
    }
  }
  if (!last){
    __syncthreads();
    if (wv < 2 && lane < 32){
      const int f = lane;
      const int nx = l + 1;
      const float* W = ((wv == 0) ? P.e1w : P.c1w) + nx*2112 + f*66;
      float sv = ((wv == 0) ? P.e1b : P.c1b)[nx*32 + f], su = 0.f;
#pragma unroll
      for (int k = 0; k < 32; ++k){ sv = fmaf(s_hl[k], W[k], sv); su = fmaf(s_hl[k], W[32+k], su); }
      if (wv == 0){ vepN[(size_t)nid*32 + f] = sv; ueN[(size_t)nid*32 + f] = su; }
      else        { vcpN[(size_t)nid*32 + f] = sv; ucN[(size_t)nid*32 + f] = su; }
    }
  }
}

extern "C" void kernel_launch(void* const* d_in, const int* in_sizes, int n_in,
                              void* d_out, int out_size, void* d_ws, size_t ws_size,
                              hipStream_t stream)
{
  float* ws   = (float*)d_ws;

  KP P;
  P.xyz      = (const float*)d_in[0];
  P.pdf      = (const float*)d_in[1];
  P.t        = (const float*)d_in[2];
  P.emb_in_w = (const float*)d_in[3];
  P.emb_in_b = (const float*)d_in[4];
  P.emb_out_w= (const float*)d_in[5];
  P.emb_out_b= (const float*)d_in[6];
  P.x_out_w  = (const float*)d_in[7];
  P.x_out_b  = (const float*)d_in[8];
  P.pdf_w    = (const float*)d_in[9];
  P.pdf_b    = (const float*)d_in[10];
  P.g1w      = (const float*)d_in[11];
  P.g1b      = (const float*)d_in[12];
  P.g2w      = (const float*)d_in[13];
  P.g2b      = (const float*)d_in[14];
  P.g3w      = (const float*)d_in[15];
  P.g3b      = (const float*)d_in[16];
  P.gamma0   = (const float*)d_in[17];
  P.gamma1   = (const float*)d_in[18];
  P.lnhg     = (const float*)d_in[19];
  P.lnhb     = (const float*)d_in[20];
  P.lnxg     = (const float*)d_in[21];
  P.lnxb     = (const float*)d_in[22];
  P.e1w      = (const float*)d_in[23];
  P.e1b      = (const float*)d_in[24];
  P.e2w      = (const float*)d_in[25];
  P.e2b      = (const float*)d_in[26];
  P.eiw      = (const float*)d_in[27];
  P.eib      = (const float*)d_in[28];
  P.n1w      = (const float*)d_in[29];
  P.n1b      = (const float*)d_in[30];
  P.n2w      = (const float*)d_in[31];
  P.n2b      = (const float*)d_in[32];
  P.c1w      = (const float*)d_in[33];
  P.c1b      = (const float*)d_in[34];
  P.c2w      = (const float*)d_in[35];
  P.c2b      = (const float*)d_in[36];
  P.c3w      = (const float*)d_in[37];
  P.c3b      = (const float*)d_in[38];

  P.temb = ws;                              // 8
  P.pdfe = ws + 8;                          // 80 (pad to 96)
  P.e2wb = (unsigned short*)(ws + 96);      // 4096 ushort
  P.c2wb = P.e2wb + 4096;                   // 4096 ushort
  float* p = ws + 96 + 4096;                // (8192 ushort = 4096 floats)
  P.hln0 = p; p += NTOT*32;
  P.hln1 = p; p += NTOT*32;
  P.ue0  = p; p += NTOT*32;
  P.uc0  = p; p += NTOT*32;
  P.vep0 = p; p += NTOT*32;
  P.vcp0 = p; p += NTOT*32;
  P.ue1  = p; p += NTOT*32;
  P.uc1  = p; p += NTOT*32;
  P.vep1 = p; p += NTOT*32;
  P.vcp1 = p; p += NTOT*32;
  P.xb0  = p; p += NTOT*3;
  P.xb1  = p; p += NTOT*3;
  P.out  = (float*)d_out;

  k_prelude<<<120, 128, 0, stream>>>(P);
  k_embed<<<NTOT, 128, 0, stream>>>(P);

  float* xcur = P.xb0; float* xnxt = P.xb1;
  float* hlnC = P.hln0; float* hlnN = P.hln1;
  float* ueC = P.ue0;  float* ucC = P.uc0;  float* vepC = P.vep0; float* vcpC = P.vcp0;
  float* ueN = P.ue1;  float* ucN = P.uc1;  float* vepN = P.vep1; float* vcpN = P.vcp1;
  for (int l = 0; l < 4; ++l){
    k_layer<<<NTOT, 256, 0, stream>>>(P, l, (l == 3) ? 1 : 0, xcur, xnxt,
        hlnC, hlnN, ueC, ucC, vepC, vcpC, ueN, ucN, vepN, vcpN);
    float* tp;
    tp = hlnC; hlnC = hlnN; hlnN = tp;
    tp = ueC;  ueC  = ueN;  ueN  = tp;
    tp = ucC;  ucC  = ucN;  ucN  = tp;
    tp = vepC; vepC = vepN; vepN = tp;
    tp = vcpC; vcpC = vcpN; vcpN = tp;
    tp = xcur; xcur = xnxt; xnxt = tp;
  }
}